// Round 8
// baseline (582.181 us; speedup 1.0000x reference)
//
#include <hip/hip_runtime.h>

#define S 132                 // padded LDS row stride (floats) for gemm tiles
#define SCALE 10.0f           // 1 / TEMPERATURE
#define EPS_MARGIN 0.011f     // 2*bf16-dot err (0.008) + 2 u16 round-ups + slack
#define PAIR_CAP 32768

typedef __attribute__((ext_vector_type(8))) short short8;
typedef __attribute__((ext_vector_type(4))) float floatx4;

#define MFMA16(a, b, c) __builtin_amdgcn_mfma_f32_16x16x32_bf16((a), (b), (c), 0, 0, 0)

// ---------- helpers ----------
__device__ __forceinline__ unsigned int ordered_bits(float f) {
    unsigned int b = __float_as_uint(f);
    return (b & 0x80000000u) ? ~b : (b | 0x80000000u);
}
__device__ __forceinline__ float from_ordered(unsigned int u) {
    return __uint_as_float((u & 0x80000000u) ? (u ^ 0x80000000u) : ~u);
}
__device__ __forceinline__ short bf_rne(float x) {   // fp32 -> bf16 bits, RNE
    unsigned int u = __float_as_uint(x);
    return (short)((u + 0x7FFFu + ((u >> 16) & 1u)) >> 16);
}
__device__ __forceinline__ float bf2f(short s) {
    return __uint_as_float(((unsigned int)(unsigned short)s) << 16);
}

// ---------- K1: l2-normalize p1,p2 -> pn fp32 + pnb bf16; init state --------
__global__ void k_prep(const float* __restrict__ p1, const float* __restrict__ p2,
                       float* __restrict__ pn, short* __restrict__ pnb,
                       unsigned long long* __restrict__ best,
                       unsigned int* __restrict__ paircnt, float* __restrict__ sums) {
    int row = blockIdx.x;               // 0..4095
    int t = threadIdx.x;                // 0..63
    const float* src = (row < 2048) ? (p1 + (size_t)row * 128)
                                    : (p2 + (size_t)(row - 2048) * 128);
    float2 v = ((const float2*)src)[t];
    float ss = v.x * v.x + v.y * v.y;
    #pragma unroll
    for (int o = 32; o; o >>= 1) ss += __shfl_xor(ss, o);
    float inv = 1.0f / sqrtf(ss);
    float2 o2; o2.x = v.x * inv; o2.y = v.y * inv;
    ((float2*)(pn + (size_t)row * 128))[t] = o2;
    unsigned int pk = (unsigned int)(unsigned short)bf_rne(o2.x)
                    | ((unsigned int)(unsigned short)bf_rne(o2.y) << 16);
    ((unsigned int*)(pnb + (size_t)row * 128))[t] = pk;
    if (t == 0) { best[row] = 0ULL; if (row == 0) *paircnt = 0u; }
    if (row < 128) sums[row * 64 + t] = 0.0f;
}

// ---------- K2: queue fp32 -> qb bf16 ----------
__global__ void k_qcvt(const float* __restrict__ queue, short* __restrict__ qb) {
    size_t i = ((size_t)blockIdx.x * 256 + threadIdx.x) * 8;
    float4 f0 = *(const float4*)(queue + i);
    float4 f1 = *(const float4*)(queue + i + 4);
    short8 o;
    o[0] = bf_rne(f0.x); o[1] = bf_rne(f0.y); o[2] = bf_rne(f0.z); o[3] = bf_rne(f0.w);
    o[4] = bf_rne(f1.x); o[5] = bf_rne(f1.y); o[6] = bf_rne(f1.z); o[7] = bf_rne(f1.w);
    *(short8*)(qb + i) = o;
}

// ---------- 16-q tile: k-outer / rf-inner (8-way ILP), fmax into chunk maxes -
__device__ __forceinline__ void tile_acc(const short8 A[8][4], const short8 B[4],
                                         float rmaxc[8][4]) {
    floatx4 acc[8];
    floatx4 zero = {0.0f, 0.0f, 0.0f, 0.0f};
    #pragma unroll
    for (int rf = 0; rf < 8; ++rf) acc[rf] = MFMA16(A[rf][0], B[0], zero);
    #pragma unroll
    for (int rf = 0; rf < 8; ++rf) acc[rf] = MFMA16(A[rf][1], B[1], acc[rf]);
    #pragma unroll
    for (int rf = 0; rf < 8; ++rf) acc[rf] = MFMA16(A[rf][2], B[2], acc[rf]);
    #pragma unroll
    for (int rf = 0; rf < 8; ++rf) acc[rf] = MFMA16(A[rf][3], B[3], acc[rf]);
    #pragma unroll
    for (int rf = 0; rf < 8; ++rf)
        #pragma unroll
        for (int r = 0; r < 4; ++r) rmaxc[rf][r] = fmaxf(rmaxc[rf][r], acc[rf][r]);
}

// ---------- K3: SINGLE bf16 MFMA screen -> per-(row, 64q-chunk) max u16 ------
// Block = 4 waves x same 1024-q strip (B shared via L1/L2); wave owns 128 rows
// (A in 128 VGPRs). Grid 512 = 8 rowblocks x 64 qsplits, XCD-swizzled so each
// XCD touches 8 qsplits = 2 MB of qb (L2-resident). Chunk max rounded UP.
__global__ __launch_bounds__(256, 2) void k_screen(const short* __restrict__ pnb,
                                                   const short* __restrict__ qb,
                                                   unsigned short* __restrict__ cm) {
    int tid = threadIdx.x;
    int lane = tid & 63, wv = tid >> 6;
    int n16 = lane & 15, quad = lane >> 4;

    int id = blockIdx.x;                // 0..511
    int xcd = id & 7;
    int g = id >> 3;                    // 0..63
    int rowblk = g & 7;                 // 8 rowblocks of 512 rows
    int qsub = g >> 3;                  // 0..7
    int qsplit = xcd * 8 + qsub;        // 64 qsplits of 1024 q
    int rowbase = rowblk * 512 + wv * 128;
    int qstart = qsplit * 1024;

    short8 A[8][4];                     // 128 VGPRs, direct bf16 loads
    #pragma unroll
    for (int rf = 0; rf < 8; ++rf) {
        const short* ap = pnb + (size_t)(rowbase + rf * 16 + n16) * 128 + quad * 8;
        #pragma unroll
        for (int kk = 0; kk < 4; ++kk)
            A[rf][kk] = *(const short8*)(ap + kk * 32);
    }

    float rmaxc[8][4];
    #pragma unroll
    for (int rf = 0; rf < 8; ++rf)
        #pragma unroll
        for (int r = 0; r < 4; ++r) rmaxc[rf][r] = -1e30f;

    const short* lp = qb + (size_t)(qstart + n16) * 128 + quad * 8;
    short8 B0[4], B1[4];
    #pragma unroll
    for (int k = 0; k < 4; ++k) B0[k] = *(const short8*)(lp + 32 * k);

    for (int tp = 0; tp < 16; ++tp) {   // 16 chunks of 64 q (4 tiles each)
        if ((tp & 3) == 0) __syncthreads();   // keep waves converged for B sharing
        const short* p1 = lp + 2048;
        #pragma unroll
        for (int k = 0; k < 4; ++k) B1[k] = *(const short8*)(p1 + 32 * k);
        tile_acc(A, B0, rmaxc);
        const short* p2 = lp + 4096;
        #pragma unroll
        for (int k = 0; k < 4; ++k) B0[k] = *(const short8*)(p2 + 32 * k);
        tile_acc(A, B1, rmaxc);
        const short* p3 = lp + 6144;
        #pragma unroll
        for (int k = 0; k < 4; ++k) B1[k] = *(const short8*)(p3 + 32 * k);
        tile_acc(A, B0, rmaxc);
        const short* p4 = lp + 8192;    // tile +4 (tail over-read lands in pnb)
        #pragma unroll
        for (int k = 0; k < 4; ++k) B0[k] = *(const short8*)(p4 + 32 * k);
        tile_acc(A, B1, rmaxc);
        lp = p4;

        // chunk epilogue: reduce over n16, store round-up u16, reset
        int cidx = qsplit * 16 + tp;
        #pragma unroll
        for (int rf = 0; rf < 8; ++rf)
            #pragma unroll
            for (int r = 0; r < 4; ++r) {
                float v = rmaxc[rf][r];
                v = fmaxf(v, __shfl_xor(v, 1));
                v = fmaxf(v, __shfl_xor(v, 2));
                v = fmaxf(v, __shfl_xor(v, 4));
                v = fmaxf(v, __shfl_xor(v, 8));
                if (n16 == 0) {
                    unsigned int s = (ordered_bits(v) >> 16) + 1u;
                    if (s > 0xFFFFu) s = 0xFFFFu;
                    cm[(size_t)(rowbase + rf * 16 + quad * 4 + r) * 1024 + cidx]
                        = (unsigned short)s;
                }
                rmaxc[rf][r] = -1e30f;
            }
    }
}

// ---------- K4: per row: rowmax over 1024 chunk maxes -> flag pairs ----------
__global__ void k_select(const unsigned short* __restrict__ cm,
                         unsigned int* __restrict__ paircnt,
                         unsigned int* __restrict__ pairs) {
    int row = blockIdx.x;               // 0..4095
    int l = threadIdx.x;                // 0..63
    const uint4* base = (const uint4*)(cm + (size_t)row * 1024);
    uint4 a = base[l * 2], b = base[l * 2 + 1];     // chunks l*16 .. l*16+15
    unsigned int va[8] = {a.x, a.y, a.z, a.w, b.x, b.y, b.z, b.w};
    unsigned int m = 0;
    #pragma unroll
    for (int i = 0; i < 8; ++i) {
        m = max(m, va[i] & 0xFFFFu);
        m = max(m, va[i] >> 16);
    }
    #pragma unroll
    for (int o = 32; o; o >>= 1) m = max(m, __shfl_xor(m, o));
    float vmax = from_ordered((m - 1u) << 16);      // <= true bf16 rowmax
    unsigned int thr = ordered_bits(vmax - EPS_MARGIN) >> 16;
    #pragma unroll
    for (int i = 0; i < 8; ++i) {
        if ((va[i] & 0xFFFFu) >= thr) {
            unsigned int pos = atomicAdd(paircnt, 1u);
            if (pos < PAIR_CAP) pairs[pos] = ((unsigned int)row << 10) | (l * 16 + i * 2);
        }
        if ((va[i] >> 16) >= thr) {
            unsigned int pos = atomicAdd(paircnt, 1u);
            if (pos < PAIR_CAP) pairs[pos] = ((unsigned int)row << 10) | (l * 16 + i * 2 + 1);
        }
    }
}

// ---------- K5: exact fp32 re-rank of flagged 64-q chunks --------------------
// One block (256 thr) per pair, grid-stride. Thread t: q = q0 + t/4, dims
// (t%4)*32..+32; shfl-combine 4 lanes -> dot; packed max -> atomicMax(best).
__global__ __launch_bounds__(256) void k_cexact(const float* __restrict__ pn,
                                                const float* __restrict__ queue,
                                                const unsigned int* __restrict__ paircnt,
                                                const unsigned int* __restrict__ pairs,
                                                unsigned long long* __restrict__ best) {
    __shared__ unsigned long long wmax[4];
    int tid = threadIdx.x, wv = tid >> 6, lane = tid & 63;
    unsigned int n = *paircnt; if (n > PAIR_CAP) n = PAIR_CAP;
    for (unsigned int p = blockIdx.x; p < n; p += gridDim.x) {
        unsigned int pr = pairs[p];
        unsigned int row = pr >> 10;
        unsigned int q = ((pr & 1023u) << 6) + (tid >> 2);
        int kq = (tid & 3) * 32;
        const float4* qs = (const float4*)(queue + (size_t)q * 128 + kq);
        const float4* ps = (const float4*)(pn + (size_t)row * 128 + kq);
        float s = 0.0f;
        #pragma unroll
        for (int j = 0; j < 8; ++j) {
            float4 x = ps[j], y = qs[j];
            s += x.x * y.x + x.y * y.y + x.z * y.z + x.w * y.w;
        }
        s += __shfl_xor(s, 1);
        s += __shfl_xor(s, 2);          // all 4 lanes of the group hold full dot
        unsigned long long pk = ((unsigned long long)ordered_bits(s) << 32)
                              | (unsigned long long)(unsigned int)(~q);
        #pragma unroll
        for (int o = 32; o; o >>= 1) {
            unsigned long long o2 = __shfl_xor(pk, o);
            if (o2 > pk) pk = o2;
        }
        if (lane == 0) wmax[wv] = pk;
        __syncthreads();
        if (tid == 0) {
            unsigned long long m0 = wmax[0];
            if (wmax[1] > m0) m0 = wmax[1];
            if (wmax[2] > m0) m0 = wmax[2];
            if (wmax[3] > m0) m0 = wmax[3];
            atomicMax(&best[row], m0);
        }
        __syncthreads();
    }
}

// ---------- K6: gather nn rows from queue -> bf16 ----------
__global__ void k_gather(const float* __restrict__ queue,
                         const unsigned long long* __restrict__ best,
                         short* __restrict__ nnb) {
    int row = blockIdx.x;
    int t = threadIdx.x;
    unsigned int idx = ~(unsigned int)(best[row] & 0xFFFFFFFFull);
    idx &= 0xFFFFu;
    float2 v = ((const float2*)(queue + (size_t)idx * 128))[t];
    unsigned int pk = (unsigned int)(unsigned short)bf_rne(v.x)
                    | ((unsigned int)(unsigned short)bf_rne(v.y) << 16);
    ((unsigned int*)(nnb + (size_t)row * 128))[t] = pk;
}

// ---------- K7: fused A(bf16) @ B(fp32)^T -> exp-partial row/col sums --------
__global__ __launch_bounds__(256) void k_gemm_lse(const short* __restrict__ Ab,
                                                  const float* __restrict__ B,
                                                  float* __restrict__ rowsum,
                                                  float* __restrict__ colsum,
                                                  float* __restrict__ diag) {
    __shared__ __align__(16) float al[64 * S];
    __shared__ __align__(16) float bl[64 * S];
    __shared__ float red[64][17];
    int tid = threadIdx.x;
    const short8* asrc = (const short8*)(Ab + (size_t)blockIdx.x * 64 * 128);
    #pragma unroll
    for (int i = tid; i < 1024; i += 256) {
        short8 v = asrc[i];
        int r = i >> 4, c = (i & 15) * 8;
        float* dst = &al[r * S + c];
        #pragma unroll
        for (int j = 0; j < 8; ++j) dst[j] = bf2f(v[j]);
    }
    const float4* bsrc = (const float4*)(B + (size_t)blockIdx.y * 64 * 128);
    #pragma unroll
    for (int i = tid; i < 2048; i += 256) {
        int r = i >> 5, c = i & 31;
        *(float4*)&bl[r * S + c * 4] = bsrc[i];
    }
    __syncthreads();
    int ty = tid >> 4, tx = tid & 15;
    float acc[4][4] = {};
    #pragma unroll 2
    for (int k = 0; k < 128; k += 4) {
        float4 a[4], b[4];
        #pragma unroll
        for (int i = 0; i < 4; ++i) a[i] = *(const float4*)&al[(ty + 16 * i) * S + k];
        #pragma unroll
        for (int j = 0; j < 4; ++j) b[j] = *(const float4*)&bl[(tx + 16 * j) * S + k];
        #pragma unroll
        for (int i = 0; i < 4; ++i)
            #pragma unroll
            for (int j = 0; j < 4; ++j)
                acc[i][j] += a[i].x * b[j].x + a[i].y * b[j].y +
                             a[i].z * b[j].z + a[i].w * b[j].w;
    }
    int rowbase = blockIdx.x * 64, colbase = blockIdx.y * 64;

    float e[4][4], rs[4], cs[4];
    #pragma unroll
    for (int i = 0; i < 4; ++i) { rs[i] = 0.0f; cs[i] = 0.0f; }
    #pragma unroll
    for (int i = 0; i < 4; ++i)
        #pragma unroll
        for (int j = 0; j < 4; ++j) {
            e[i][j] = __expf(acc[i][j] * SCALE - 10.0f);
            rs[i] += e[i][j];
        }
    #pragma unroll
    for (int j = 0; j < 4; ++j)
        #pragma unroll
        for (int i = 0; i < 4; ++i) cs[j] += e[i][j];

    if (rowbase == colbase && ty == tx) {
        #pragma unroll
        for (int i = 0; i < 4; ++i) diag[rowbase + ty + 16 * i] = acc[i][i];
    }

    #pragma unroll
    for (int i = 0; i < 4; ++i) red[ty + 16 * i][tx] = rs[i];
    __syncthreads();
    if (tid < 64) {
        float s = 0.0f;
        #pragma unroll
        for (int x = 0; x < 16; ++x) s += red[tid][x];
        atomicAdd(&rowsum[rowbase + tid], s);
    }
    __syncthreads();
    #pragma unroll
    for (int j = 0; j < 4; ++j) red[tx + 16 * j][ty] = cs[j];
    __syncthreads();
    if (tid < 64) {
        float s = 0.0f;
        #pragma unroll
        for (int x = 0; x < 16; ++x) s += red[tid][x];
        atomicAdd(&colsum[colbase + tid], s);
    }
}

// ---------- K8: final loss ----------
__global__ void k_final(const float* __restrict__ sums,
                        const float* __restrict__ dg1, const float* __restrict__ dg2,
                        float* __restrict__ out) {
    int idx = blockIdx.x * 256 + threadIdx.x;    // 0..8191
    int seg = idx >> 11, r = idx & 2047;
    float s = sums[seg * 2048 + r];
    float d = (seg < 2) ? dg1[r] : dg2[r];
    out[idx] = 10.0f + logf(s) - d * SCALE;
}

extern "C" void kernel_launch(void* const* d_in, const int* in_sizes, int n_in,
                              void* d_out, int out_size, void* d_ws, size_t ws_size,
                              hipStream_t stream) {
    const float* p1    = (const float*)d_in[0];   // [2048,128]
    const float* p2    = (const float*)d_in[1];   // [2048,128]
    const float* queue = (const float*)d_in[2];   // [65536,128]
    float* out = (float*)d_out;                   // [8192]

    char* w = (char*)d_ws;                        // footprint ~28.5 MiB
    float* pn  = (float*)w;                               // 2 MB  fp32 [4096,128]
    short* nnb = (short*)(w + (2u << 20));                // 1 MB  bf16 [4096,128]
    short* qb  = (short*)(w + (3u << 20));                // 16 MB bf16 [65536,128]
    short* pnb = (short*)(w + (19u << 20));               // 1 MB  bf16 [4096,128]
    unsigned short* cm = (unsigned short*)(w + (20u << 20)); // 8 MB u16 [4096,1024]
    char* b2 = w + (28u << 20);
    unsigned long long* best = (unsigned long long*)b2;             // 32 KB
    unsigned int* paircnt = (unsigned int*)(b2 + (32u << 10));      // 256 B
    unsigned int* pairs = (unsigned int*)(b2 + (33u << 10));        // 128 KB
    float* sums = (float*)(b2 + (161u << 10));                      // 32 KB
    float* dg1  = sums + 8192;                                      // 8 KB
    float* dg2  = dg1 + 2048;                                       // 8 KB

    k_prep<<<4096, 64, 0, stream>>>(p1, p2, pn, pnb, best, paircnt, sums);
    k_qcvt<<<4096, 256, 0, stream>>>(queue, qb);
    k_screen<<<512, 256, 0, stream>>>(pnb, qb, cm);
    k_select<<<4096, 64, 0, stream>>>(cm, paircnt, pairs);
    k_cexact<<<2048, 256, 0, stream>>>(pn, queue, paircnt, pairs, best);
    k_gather<<<4096, 64, 0, stream>>>(queue, best, nnb);

    // M1 = nn1 @ p2n^T : rows -> loss[0..2047], cols -> loss[2048..4095]
    k_gemm_lse<<<dim3(32, 32), 256, 0, stream>>>(nnb, pn + 2048 * 128,
                                                 sums, sums + 2048, dg1);
    // M2 = nn2 @ p1n^T : rows -> loss[4096..6143], cols -> loss[6144..8191]
    k_gemm_lse<<<dim3(32, 32), 256, 0, stream>>>(nnb + 2048 * 128, pn,
                                                 sums + 4096, sums + 6144, dg2);
    k_final<<<32, 256, 0, stream>>>(sums, dg1, dg2, out);
}

// Round 9
// 331.019 us; speedup vs baseline: 1.7588x; 1.7588x over previous
//
#include <hip/hip_runtime.h>

#define SCALE 10.0f           // 1 / TEMPERATURE
#define EPS_MARGIN 0.011f     // bf16-dot err (0.008) + u16 trunc slack
#define CAND_CAP 16384

typedef __attribute__((ext_vector_type(8))) short short8;
typedef __attribute__((ext_vector_type(4))) float floatx4;

#define MFMA16(a, b, c) __builtin_amdgcn_mfma_f32_16x16x32_bf16((a), (b), (c), 0, 0, 0)

// ---------- helpers ----------
__device__ __forceinline__ unsigned int ordered_bits(float f) {
    unsigned int b = __float_as_uint(f);
    return (b & 0x80000000u) ? ~b : (b | 0x80000000u);
}
__device__ __forceinline__ float from_ordered(unsigned int u) {
    return __uint_as_float((u & 0x80000000u) ? (u ^ 0x80000000u) : ~u);
}
__device__ __forceinline__ short bf_rne(float x) {   // fp32 -> bf16 bits, RNE
    unsigned int u = __float_as_uint(x);
    return (short)((u + 0x7FFFu + ((u >> 16) & 1u)) >> 16);
}

// ---------- K1: l2-normalize p1,p2 -> pn fp32 + pnb bf16; init state --------
__global__ void k_prep(const float* __restrict__ p1, const float* __restrict__ p2,
                       float* __restrict__ pn, short* __restrict__ pnb,
                       unsigned long long* __restrict__ best,
                       unsigned int* __restrict__ cnt, float* __restrict__ sums) {
    int row = blockIdx.x;               // 0..4095
    int t = threadIdx.x;                // 0..63
    const float* src = (row < 2048) ? (p1 + (size_t)row * 128)
                                    : (p2 + (size_t)(row - 2048) * 128);
    float2 v = ((const float2*)src)[t];
    float ss = v.x * v.x + v.y * v.y;
    #pragma unroll
    for (int o = 32; o; o >>= 1) ss += __shfl_xor(ss, o);
    float inv = 1.0f / sqrtf(ss);
    float2 o2; o2.x = v.x * inv; o2.y = v.y * inv;
    ((float2*)(pn + (size_t)row * 128))[t] = o2;
    unsigned int pk = (unsigned int)(unsigned short)bf_rne(o2.x)
                    | ((unsigned int)(unsigned short)bf_rne(o2.y) << 16);
    ((unsigned int*)(pnb + (size_t)row * 128))[t] = pk;
    if (t == 0) { best[row] = 0ULL; if (row == 0) *cnt = 0u; }
    if (row < 128) sums[row * 64 + t] = 0.0f;
}

// ---------- K2: queue fp32 -> qb bf16 ----------
__global__ void k_qcvt(const float* __restrict__ queue, short* __restrict__ qb) {
    size_t i = ((size_t)blockIdx.x * 256 + threadIdx.x) * 8;
    float4 f0 = *(const float4*)(queue + i);
    float4 f1 = *(const float4*)(queue + i + 4);
    short8 o;
    o[0] = bf_rne(f0.x); o[1] = bf_rne(f0.y); o[2] = bf_rne(f0.z); o[3] = bf_rne(f0.w);
    o[4] = bf_rne(f1.x); o[5] = bf_rne(f1.y); o[6] = bf_rne(f1.z); o[7] = bf_rne(f1.w);
    *(short8*)(qb + i) = o;
}

// ---------- 16-q tile, k-outer / rf-inner (8-way ILP), fmax into rmax --------
__device__ __forceinline__ void tile_max(const short8 A[8][4],
                                         short8 b0, short8 b1, short8 b2, short8 b3,
                                         float rmax[8][4]) {
    floatx4 acc[8];
    floatx4 zero = {0.0f, 0.0f, 0.0f, 0.0f};
    #pragma unroll
    for (int rf = 0; rf < 8; ++rf) acc[rf] = MFMA16(A[rf][0], b0, zero);
    #pragma unroll
    for (int rf = 0; rf < 8; ++rf) acc[rf] = MFMA16(A[rf][1], b1, acc[rf]);
    #pragma unroll
    for (int rf = 0; rf < 8; ++rf) acc[rf] = MFMA16(A[rf][2], b2, acc[rf]);
    #pragma unroll
    for (int rf = 0; rf < 8; ++rf) acc[rf] = MFMA16(A[rf][3], b3, acc[rf]);
    #pragma unroll
    for (int rf = 0; rf < 8; ++rf)
        #pragma unroll
        for (int r = 0; r < 4; ++r) rmax[rf][r] = fmaxf(rmax[rf][r], acc[rf][r]);
}

// ---------- K3: pass-1 screen -> per-(row,strip) bf16 max (u16, round-up) ----
// r7 MODE0 structure: 512 blocks (8 rowblocks x 64 qsplits, XCD-swizzled),
// 4 waves share a 1024-q strip, wave owns 128 rows (A in 128 VGPRs).
__global__ __launch_bounds__(256, 2) void k_smax(const short* __restrict__ pnb,
                                                 const short* __restrict__ qb,
                                                 unsigned short* __restrict__ sm) {
    int tid = threadIdx.x;
    int lane = tid & 63, wv = tid >> 6;
    int n16 = lane & 15, quad = lane >> 4;

    int id = blockIdx.x;                // 0..511
    int xcd = id & 7;
    int g = id >> 3;                    // 0..63
    int rowblk = g & 7;
    int qsub = g >> 3;
    int qsplit = xcd * 8 + qsub;        // 64 strips of 1024 q
    int rowbase = rowblk * 512 + wv * 128;
    int qstart = qsplit * 1024;

    short8 A[8][4];
    #pragma unroll
    for (int rf = 0; rf < 8; ++rf) {
        const short* ap = pnb + (size_t)(rowbase + rf * 16 + n16) * 128 + quad * 8;
        #pragma unroll
        for (int kk = 0; kk < 4; ++kk)
            A[rf][kk] = *(const short8*)(ap + kk * 32);
    }

    float rmax[8][4];
    #pragma unroll
    for (int rf = 0; rf < 8; ++rf)
        #pragma unroll
        for (int r = 0; r < 4; ++r) rmax[rf][r] = -1e30f;

    const short* lp = qb + (size_t)(qstart + n16) * 128 + quad * 8;
    short8 a0 = *(const short8*)(lp), a1 = *(const short8*)(lp + 32),
           a2 = *(const short8*)(lp + 64), a3 = *(const short8*)(lp + 96);

    for (int t = 0; t < 64; t += 2) {
        if ((t & 15) == 0) __syncthreads();    // keep waves converged for B sharing
        const short* p1p = lp + 2048;
        short8 b0 = *(const short8*)(p1p), b1 = *(const short8*)(p1p + 32),
               b2 = *(const short8*)(p1p + 64), b3 = *(const short8*)(p1p + 96);
        tile_max(A, a0, a1, a2, a3, rmax);
        const short* p2p = lp + 4096;          // tail over-read lands in pnb (safe)
        a0 = *(const short8*)(p2p); a1 = *(const short8*)(p2p + 32);
        a2 = *(const short8*)(p2p + 64); a3 = *(const short8*)(p2p + 96);
        tile_max(A, b0, b1, b2, b3, rmax);
        lp += 4096;
    }

    // end-of-kernel: reduce over n16 lanes, store round-up u16 strip max
    #pragma unroll
    for (int rf = 0; rf < 8; ++rf)
        #pragma unroll
        for (int r = 0; r < 4; ++r) {
            float v = rmax[rf][r];
            v = fmaxf(v, __shfl_xor(v, 1));
            v = fmaxf(v, __shfl_xor(v, 2));
            v = fmaxf(v, __shfl_xor(v, 4));
            v = fmaxf(v, __shfl_xor(v, 8));
            if (n16 == 0) {
                unsigned int s = (ordered_bits(v) >> 16) + 1u;
                if (s > 0xFFFFu) s = 0xFFFFu;
                sm[(size_t)(rowbase + rf * 16 + quad * 4 + r) * 64 + qsplit]
                    = (unsigned short)s;
            }
        }
}

// ---------- K4: per-row threshold from 64 strip maxes ----------
__global__ void k_thr(const unsigned short* __restrict__ sm,
                      float* __restrict__ thrf, unsigned int* __restrict__ thrU) {
    int row = blockIdx.x;               // 0..4095
    int l = threadIdx.x;                // 0..63
    unsigned int m = sm[(size_t)row * 64 + l];
    #pragma unroll
    for (int o = 32; o; o >>= 1) m = max(m, __shfl_xor(m, o));
    if (l == 0) {
        float vmax = from_ordered((m - 1u) << 16);   // <= true bf16 rowmax
        float thr = vmax - EPS_MARGIN;
        thrf[row] = thr;
        thrU[row] = ordered_bits(thr) >> 16;         // truncation -> conservative
    }
}

// ---------- K5: per-(16-row-group, strip) flag ----------
__global__ void k_flags(const unsigned short* __restrict__ sm,
                        const unsigned int* __restrict__ thrU,
                        unsigned char* __restrict__ flags) {
    int g = blockIdx.x;                 // 0..255
    int s = threadIdx.x;                // 0..63
    unsigned char f = 0;
    #pragma unroll
    for (int i = 0; i < 16; ++i) {
        int row = g * 16 + i;
        if ((unsigned int)sm[(size_t)row * 64 + s] >= thrU[row]) { f = 1; break; }
    }
    flags[g * 64 + s] = f;
}

// ---------- K6: pass-2 screen, flag-gated candidate emission -----------------
// Same shape as k_smax; per-rf 4-MFMA group runs only if its (rowgroup,strip)
// flag is set (wave-uniform branch). Emits (row,q) with acc > thrf[row].
__global__ __launch_bounds__(256, 2) void k_scand(const short* __restrict__ pnb,
                                                  const short* __restrict__ qb,
                                                  const unsigned char* __restrict__ flags,
                                                  const float* __restrict__ thrf,
                                                  unsigned int* __restrict__ cnt,
                                                  unsigned long long* __restrict__ cand) {
    int tid = threadIdx.x;
    int lane = tid & 63, wv = tid >> 6;
    int n16 = lane & 15, quad = lane >> 4;

    int id = blockIdx.x;
    int xcd = id & 7;
    int g = id >> 3;
    int rowblk = g & 7;
    int qsub = g >> 3;
    int qsplit = xcd * 8 + qsub;
    int rowbase = rowblk * 512 + wv * 128;
    int qstart = qsplit * 1024;

    // wave-uniform flag mask for the 8 rf groups
    unsigned int mask = 0;
    #pragma unroll
    for (int rf = 0; rf < 8; ++rf)
        mask |= ((unsigned int)flags[((rowbase >> 4) + rf) * 64 + qsplit]) << rf;

    short8 A[8][4];
    #pragma unroll
    for (int rf = 0; rf < 8; ++rf) {
        const short* ap = pnb + (size_t)(rowbase + rf * 16 + n16) * 128 + quad * 8;
        #pragma unroll
        for (int kk = 0; kk < 4; ++kk)
            A[rf][kk] = *(const short8*)(ap + kk * 32);
    }

    float thr[8][4];
    #pragma unroll
    for (int rf = 0; rf < 8; ++rf)
        #pragma unroll
        for (int r = 0; r < 4; ++r)
            thr[rf][r] = thrf[rowbase + rf * 16 + quad * 4 + r];

    const short* lp = qb + (size_t)(qstart + n16) * 128 + quad * 8;
    short8 bc0 = *(const short8*)(lp), bc1 = *(const short8*)(lp + 32),
           bc2 = *(const short8*)(lp + 64), bc3 = *(const short8*)(lp + 96);
    floatx4 zero = {0.0f, 0.0f, 0.0f, 0.0f};

    for (int t = 0; t < 64; ++t) {
        if ((t & 15) == 0) __syncthreads();
        const short* nlp = lp + 2048;   // tail over-read lands in pnb (safe)
        short8 bn0 = *(const short8*)(nlp), bn1 = *(const short8*)(nlp + 32),
               bn2 = *(const short8*)(nlp + 64), bn3 = *(const short8*)(nlp + 96);
        #pragma unroll
        for (int rf = 0; rf < 8; ++rf) {
            if (mask & (1u << rf)) {    // wave-uniform
                floatx4 acc = MFMA16(A[rf][0], bc0, zero);
                acc = MFMA16(A[rf][1], bc1, acc);
                acc = MFMA16(A[rf][2], bc2, acc);
                acc = MFMA16(A[rf][3], bc3, acc);
                float any = -1.0f;
                #pragma unroll
                for (int r = 0; r < 4; ++r) any = fmaxf(any, acc[r] - thr[rf][r]);
                if (__any(any > 0.0f)) {
                    #pragma unroll
                    for (int r = 0; r < 4; ++r) {
                        if (acc[r] > thr[rf][r]) {
                            unsigned int pos = atomicAdd(cnt, 1u);
                            if (pos < CAND_CAP)
                                cand[pos] = ((unsigned long long)(unsigned int)(rowbase + rf * 16 + quad * 4 + r) << 32)
                                          | (unsigned int)(qstart + t * 16 + n16);
                        }
                    }
                }
            }
        }
        bc0 = bn0; bc1 = bn1; bc2 = bn2; bc3 = bn3;
        lp = nlp;
    }
}

// ---------- K7: exact fp32 re-rank of candidates (one wave each) ----------
__global__ void k_rerank(const float* __restrict__ pn, const float* __restrict__ queue,
                         const unsigned int* __restrict__ cnt,
                         const unsigned long long* __restrict__ cand,
                         unsigned long long* __restrict__ best) {
    int widx = (blockIdx.x * 256 + threadIdx.x) >> 6;
    int lane = threadIdx.x & 63;
    unsigned int n = *cnt; if (n > CAND_CAP) n = CAND_CAP;
    if ((unsigned int)widx >= n) return;
    unsigned long long c = cand[widx];
    unsigned int row = (unsigned int)(c >> 32);
    unsigned int q = (unsigned int)c;
    float2 a = ((const float2*)(pn + (size_t)row * 128))[lane];
    float2 b = ((const float2*)(queue + (size_t)q * 128))[lane];
    float d = a.x * b.x + a.y * b.y;
    #pragma unroll
    for (int o = 32; o; o >>= 1) d += __shfl_xor(d, o);
    if (lane == 0) {
        unsigned long long pk = ((unsigned long long)ordered_bits(d) << 32)
                              | (unsigned long long)(unsigned int)(~q);
        atomicMax(&best[row], pk);
    }
}

// ---------- K8: gather nn -> bf16 + EXACT fp32 diagonal ----------
__global__ void k_gather(const float* __restrict__ queue, const float* __restrict__ pn,
                         const unsigned long long* __restrict__ best,
                         short* __restrict__ nnb,
                         float* __restrict__ dg1, float* __restrict__ dg2) {
    int row = blockIdx.x;               // 0..4095
    int t = threadIdx.x;                // 0..63
    unsigned int idx = ~(unsigned int)(best[row] & 0xFFFFFFFFull);
    idx &= 0xFFFFu;
    float2 v = ((const float2*)(queue + (size_t)idx * 128))[t];
    unsigned int pk = (unsigned int)(unsigned short)bf_rne(v.x)
                    | ((unsigned int)(unsigned short)bf_rne(v.y) << 16);
    ((unsigned int*)(nnb + (size_t)row * 128))[t] = pk;
    // exact diag: nn[row] . partner_pn[row]
    const float* partner = (row < 2048) ? pn + (size_t)(2048 + row) * 128
                                        : pn + (size_t)(row - 2048) * 128;
    float2 p = ((const float2*)partner)[t];
    float d = v.x * p.x + v.y * p.y;
    #pragma unroll
    for (int o = 32; o; o >>= 1) d += __shfl_xor(d, o);
    if (t == 0) {
        if (row < 2048) dg1[row] = d;
        else dg2[row - 2048] = d;
    }
}

// ---------- K9: MFMA gemm+LSE partials: A(bf16) x B(bf16)^T -> exp sums ------
// Grid (32,32), block 256 = 4 waves. Tile 64 rows x 64 cols; wave w owns cols
// colbase + w*16. Fixed-shift LSE (logits in [-10,10]).
__global__ __launch_bounds__(256) void k_glse(const short* __restrict__ Ab,
                                              const short* __restrict__ Bb,
                                              float* __restrict__ rowsum,
                                              float* __restrict__ colsum) {
    int tid = threadIdx.x;
    int lane = tid & 63, wv = tid >> 6;
    int n16 = lane & 15, quad = lane >> 4;
    int rowbase = blockIdx.x * 64, colbase = blockIdx.y * 64;

    short8 A[4][4], B[4];
    #pragma unroll
    for (int rf = 0; rf < 4; ++rf) {
        const short* ap = Ab + (size_t)(rowbase + rf * 16 + n16) * 128 + quad * 8;
        #pragma unroll
        for (int kk = 0; kk < 4; ++kk) A[rf][kk] = *(const short8*)(ap + kk * 32);
    }
    const short* bp = Bb + (size_t)(colbase + wv * 16 + n16) * 128 + quad * 8;
    #pragma unroll
    for (int kk = 0; kk < 4; ++kk) B[kk] = *(const short8*)(bp + kk * 32);

    floatx4 acc[4];
    floatx4 zero = {0.0f, 0.0f, 0.0f, 0.0f};
    #pragma unroll
    for (int rf = 0; rf < 4; ++rf) acc[rf] = MFMA16(A[rf][0], B[0], zero);
    #pragma unroll
    for (int rf = 0; rf < 4; ++rf) acc[rf] = MFMA16(A[rf][1], B[1], acc[rf]);
    #pragma unroll
    for (int rf = 0; rf < 4; ++rf) acc[rf] = MFMA16(A[rf][2], B[2], acc[rf]);
    #pragma unroll
    for (int rf = 0; rf < 4; ++rf) acc[rf] = MFMA16(A[rf][3], B[3], acc[rf]);

    float e[4][4], csum = 0.0f;
    #pragma unroll
    for (int rf = 0; rf < 4; ++rf)
        #pragma unroll
        for (int r = 0; r < 4; ++r) {
            e[rf][r] = __expf(acc[rf][r] * SCALE - 10.0f);
            csum += e[rf][r];
        }
    // row partials: reduce over the 16 cols (n16 lanes)
    #pragma unroll
    for (int rf = 0; rf < 4; ++rf)
        #pragma unroll
        for (int r = 0; r < 4; ++r) {
            float v = e[rf][r];
            v += __shfl_xor(v, 1);
            v += __shfl_xor(v, 2);
            v += __shfl_xor(v, 4);
            v += __shfl_xor(v, 8);
            if (n16 == 0)
                atomicAdd(&rowsum[rowbase + rf * 16 + quad * 4 + r], v);
        }
    // col partials: reduce over the 4 quads (rows)
    csum += __shfl_xor(csum, 16);
    csum += __shfl_xor(csum, 32);
    if (quad == 0)
        atomicAdd(&colsum[colbase + wv * 16 + n16], csum);
}

// ---------- K10: final loss ----------
__global__ void k_final(const float* __restrict__ sums,
                        const float* __restrict__ dg1, const float* __restrict__ dg2,
                        float* __restrict__ out) {
    int idx = blockIdx.x * 256 + threadIdx.x;    // 0..8191
    int seg = idx >> 11, r = idx & 2047;
    float s = sums[seg * 2048 + r];
    float d = (seg < 2) ? dg1[r] : dg2[r];
    out[idx] = 10.0f + logf(s) - d * SCALE;
}

extern "C" void kernel_launch(void* const* d_in, const int* in_sizes, int n_in,
                              void* d_out, int out_size, void* d_ws, size_t ws_size,
                              hipStream_t stream) {
    const float* p1    = (const float*)d_in[0];   // [2048,128]
    const float* p2    = (const float*)d_in[1];   // [2048,128]
    const float* queue = (const float*)d_in[2];   // [65536,128]
    float* out = (float*)d_out;                   // [8192]

    char* w = (char*)d_ws;                        // footprint ~20.8 MiB
    float* pn  = (float*)w;                               // 2 MB  fp32 [4096,128]
    short* nnb = (short*)(w + (2u << 20));                // 1 MB  bf16 [4096,128]
    short* qb  = (short*)(w + (3u << 20));                // 16 MB bf16 [65536,128]
    short* pnb = (short*)(w + (19u << 20));               // 1 MB  bf16 [4096,128]
    char* b2 = w + (20u << 20);
    unsigned short* sm = (unsigned short*)b2;                       // 512 KB
    float* thrf = (float*)(b2 + (512u << 10));                      // 16 KB
    unsigned int* thrU = (unsigned int*)(b2 + (528u << 10));        // 16 KB
    unsigned char* flags = (unsigned char*)(b2 + (544u << 10));     // 16 KB
    unsigned long long* best = (unsigned long long*)(b2 + (560u << 10)); // 32 KB
    unsigned int* cnt = (unsigned int*)(b2 + (592u << 10));         // 256 B
    unsigned long long* cand = (unsigned long long*)(b2 + (608u << 10)); // 128 KB
    float* sums = (float*)(b2 + (736u << 10));                      // 32 KB
    float* dg1  = sums + 8192;                                      // 8 KB
    float* dg2  = dg1 + 2048;                                       // 8 KB

    k_prep<<<4096, 64, 0, stream>>>(p1, p2, pn, pnb, best, cnt, sums);
    k_qcvt<<<4096, 256, 0, stream>>>(queue, qb);
    k_smax<<<512, 256, 0, stream>>>(pnb, qb, sm);
    k_thr<<<4096, 64, 0, stream>>>(sm, thrf, thrU);
    k_flags<<<256, 64, 0, stream>>>(sm, thrU, flags);
    k_scand<<<512, 256, 0, stream>>>(pnb, qb, flags, thrf, cnt, cand);
    k_rerank<<<4096, 256, 0, stream>>>(pn, queue, cnt, cand, best);
    k_gather<<<4096, 64, 0, stream>>>(queue, pn, best, nnb, dg1, dg2);

    // M1 = nn1 @ p2n^T : rows -> loss[0..2047], cols -> loss[2048..4095]
    k_glse<<<dim3(32, 32), 256, 0, stream>>>(nnb, pnb + 2048 * 128,
                                             sums, sums + 2048);
    // M2 = nn2 @ p1n^T : rows -> loss[4096..6143], cols -> loss[6144..8191]
    k_glse<<<dim3(32, 32), 256, 0, stream>>>(nnb + 2048 * 128, pnb,
                                             sums + 4096, sums + 6144);
    k_final<<<32, 256, 0, stream>>>(sums, dg1, dg2, out);
}